// Round 1
// baseline (677.174 us; speedup 1.0000x reference)
//
#include <hip/hip_runtime.h>
#include <hip/hip_bf16.h>
#include <stdint.h>

typedef __bf16 bf16_t;
typedef __bf16 bf16x8 __attribute__((ext_vector_type(8)));
typedef float f32x4 __attribute__((ext_vector_type(4)));
typedef unsigned int u32;

// ---------------------------------------------------------------------------
// async global->LDS, 16B per lane. LDS dest is wave-uniform base + lane*16
// (we pass per-lane ptr = base + t*16 so lane0's value IS the wave base).
// ---------------------------------------------------------------------------
__device__ __forceinline__ void async_copy16(void* lds, const void* gmem) {
    __builtin_amdgcn_global_load_lds(
        (const __attribute__((address_space(1))) u32*)gmem,
        (__attribute__((address_space(3))) u32*)lds,
        16, 0, 0);
}

// ---------------------------------------------------------------------------
// x (f32) -> bf16, vectorized 8 elems/thread/iter
// ---------------------------------------------------------------------------
__global__ void cvt_x_kernel(const float* __restrict__ in,
                             bf16_t* __restrict__ out, int n8) {
    int stride = gridDim.x * blockDim.x;
    for (int i = blockIdx.x * blockDim.x + threadIdx.x; i < n8; i += stride) {
        const float4* p = (const float4*)in + 2 * (size_t)i;
        float4 a = p[0], b = p[1];
        bf16x8 o;
        o[0] = (__bf16)a.x; o[1] = (__bf16)a.y; o[2] = (__bf16)a.z; o[3] = (__bf16)a.w;
        o[4] = (__bf16)b.x; o[5] = (__bf16)b.y; o[6] = (__bf16)b.z; o[7] = (__bf16)b.w;
        *(bf16x8*)(out + 8 * (size_t)i) = o;
    }
}

// ---------------------------------------------------------------------------
// w (f32) * per-128x128-block scale -> bf16 (scale folded into weight)
// ---------------------------------------------------------------------------
__global__ void cvt_w_kernel(const float* __restrict__ w,
                             const float* __restrict__ wsc,
                             bf16_t* __restrict__ out, int n8, int K, int KB) {
    int stride = gridDim.x * blockDim.x;
    for (int i = blockIdx.x * blockDim.x + threadIdx.x; i < n8; i += stride) {
        int e = i * 8;              // flat element index (8-aligned, within a k-block)
        int row = e / K;
        int col = e - row * K;
        float s = wsc[(row >> 7) * KB + (col >> 7)];
        const float4* p = (const float4*)w + 2 * (size_t)i;
        float4 a = p[0], b = p[1];
        bf16x8 o;
        o[0] = (__bf16)(a.x * s); o[1] = (__bf16)(a.y * s);
        o[2] = (__bf16)(a.z * s); o[3] = (__bf16)(a.w * s);
        o[4] = (__bf16)(b.x * s); o[5] = (__bf16)(b.y * s);
        o[6] = (__bf16)(b.z * s); o[7] = (__bf16)(b.w * s);
        *(bf16x8*)(out + 8 * (size_t)i) = o;
    }
}

// ---------------------------------------------------------------------------
// m97-structure GEMM: C[M,N] = A[M,K] * B[N,K]^T + bias
// 128x128 tile, BK=32, 4 waves (2x2), each wave 64x64 via 4x4 16x16x32 frags.
// global_load_lds width=16, linear LDS, 2 barriers per K-step.
// ---------------------------------------------------------------------------
#define BM 128
#define BN 128
#define BK 32

__global__ __launch_bounds__(256) void gemm_bt_bias(
    const bf16_t* __restrict__ A,   // [M,K] row-major
    const bf16_t* __restrict__ B,   // [N,K] row-major
    const float* __restrict__ bias, // [N]
    float* __restrict__ C,          // [M,N] row-major
    int M, int N, int K) {
    __shared__ bf16_t As[BM * BK];  // 8 KB, linear row-major [128][32]
    __shared__ bf16_t Bs[BN * BK];  // 8 KB

    const int t = threadIdx.x;
    const int lane = t & 63;
    const int wave = t >> 6;
    const int wr = wave >> 1;       // wave row (0..1)
    const int wc = wave & 1;        // wave col (0..1)

    const long arow = (long)blockIdx.y * BM;
    const long bcol = (long)blockIdx.x * BN;

    // staging: thread t covers LDS elems [t*8, t*8+8) (+2048 on round 1)
    const int r0 = t >> 2;          // tile row, round 0 (0..63)
    const int c0 = (t & 3) * 8;     // k-col within tile
    const bf16_t* Ag = A + (arow + r0) * K + c0;
    const bf16_t* Bg = B + (bcol + r0) * K + c0;
    bf16_t* Al = As + t * 8;
    bf16_t* Bl = Bs + t * 8;
    const size_t gstep = (size_t)64 * K;   // +64 rows for round 1

    f32x4 acc[4][4];
#pragma unroll
    for (int m = 0; m < 4; ++m)
#pragma unroll
        for (int n = 0; n < 4; ++n) {
            f32x4 z = {0.f, 0.f, 0.f, 0.f};
            acc[m][n] = z;
        }

    const int la = lane & 15;            // row/col-in-frag
    const int kg = (lane >> 4) * 8;      // k-offset in frag

    for (int k0 = 0; k0 < K; k0 += BK) {
        async_copy16(Al,        Ag + k0);
        async_copy16(Al + 2048, Ag + k0 + gstep);
        async_copy16(Bl,        Bg + k0);
        async_copy16(Bl + 2048, Bg + k0 + gstep);
        __syncthreads();

        bf16x8 af[4], bfv[4];
#pragma unroll
        for (int m = 0; m < 4; ++m)
            af[m] = *(const bf16x8*)(As + (wr * 64 + m * 16 + la) * BK + kg);
#pragma unroll
        for (int n = 0; n < 4; ++n)
            bfv[n] = *(const bf16x8*)(Bs + (wc * 64 + n * 16 + la) * BK + kg);

#pragma unroll
        for (int m = 0; m < 4; ++m)
#pragma unroll
            for (int n = 0; n < 4; ++n)
                acc[m][n] = __builtin_amdgcn_mfma_f32_16x16x32_bf16(
                    af[m], bfv[n], acc[m][n], 0, 0, 0);
        __syncthreads();
    }

    // epilogue: D col = lane&15, row = 4*(lane>>4) + reg   [m89-verified]
    const int lg = lane >> 4;
#pragma unroll
    for (int n = 0; n < 4; ++n) {
        const long col = bcol + wc * 64 + n * 16 + la;
        const float bv = bias[col];
#pragma unroll
        for (int m = 0; m < 4; ++m) {
            const long row = arow + wr * 64 + m * 16 + lg * 4;
            float* cp = C + row * (long)N + col;
#pragma unroll
            for (int r = 0; r < 4; ++r)
                cp[(size_t)r * N] = acc[m][n][r] + bv;
        }
    }
}

// ---------------------------------------------------------------------------
// fallback: naive f32 (only if workspace too small / shapes not tileable)
// ---------------------------------------------------------------------------
__global__ void naive_kernel(const float* __restrict__ x,
                             const float* __restrict__ w,
                             const float* __restrict__ wsc,
                             const float* __restrict__ bias,
                             float* __restrict__ out,
                             int T, int N, int K, int KB) {
    long i = (long)blockIdx.x * blockDim.x + threadIdx.x;
    if (i >= (long)T * N) return;
    int tt = (int)(i / N), n = (int)(i % N);
    float accum = 0.f;
    for (int kb = 0; kb < KB; ++kb) {
        float s = wsc[(n >> 7) * KB + kb];
        float p = 0.f;
        const float* xp = x + (long)tt * K + kb * 128;
        const float* wp = w + (long)n * K + kb * 128;
        for (int k = 0; k < 128; ++k) p += xp[k] * wp[k];
        accum += p * s;
    }
    out[i] = accum + bias[n];
}

extern "C" void kernel_launch(void* const* d_in, const int* in_sizes, int n_in,
                              void* d_out, int out_size, void* d_ws, size_t ws_size,
                              hipStream_t stream) {
    const float* x    = (const float*)d_in[0];
    const float* wq   = (const float*)d_in[1];
    const float* wsc  = (const float*)d_in[2];
    const float* bias = (const float*)d_in[3];
    float* out = (float*)d_out;

    const int N = in_sizes[3];
    const int K = in_sizes[1] / N;
    const int T = in_sizes[0] / K;
    const int KB = K / 128;

    const size_t need = ((size_t)T * K + (size_t)N * K) * sizeof(bf16_t);
    const bool tileable = (T % BM == 0) && (N % BN == 0) && (K % BK == 0) &&
                          (K % 128 == 0);

    if (ws_size < need || !tileable) {
        long total = (long)T * N;
        int blocks = (int)((total + 255) / 256);
        naive_kernel<<<blocks, 256, 0, stream>>>(x, wq, wsc, bias, out, T, N, K, KB);
        return;
    }

    bf16_t* xb = (bf16_t*)d_ws;
    bf16_t* wb = xb + (size_t)T * K;

    cvt_x_kernel<<<2048, 256, 0, stream>>>(x, xb, T * (K / 8));
    cvt_w_kernel<<<2048, 256, 0, stream>>>(wq, wsc, wb, N * (K / 8), K, KB);

    dim3 grid(N / BN, T / BM);
    gemm_bt_bias<<<grid, 256, 0, stream>>>(xb, wb, bias, out, T, N, K);
}

// Round 2
// 497.599 us; speedup vs baseline: 1.3609x; 1.3609x over previous
//
#include <hip/hip_runtime.h>
#include <hip/hip_bf16.h>
#include <stdint.h>

typedef __bf16 bf16_t;
typedef __bf16 bf16x8 __attribute__((ext_vector_type(8)));
typedef float f32x4 __attribute__((ext_vector_type(4)));
typedef unsigned int u32;

// ---------------------------------------------------------------------------
// async global->LDS, 16B per lane. HW dest = wave-uniform base + lane*16;
// we pass per-lane ptr linear in tid so lane stride is exactly 16B.
// Global SOURCE is per-lane -> swizzled LDS content via pre-swizzled source.
// ---------------------------------------------------------------------------
__device__ __forceinline__ void async_copy16(void* lds, const void* gmem) {
    __builtin_amdgcn_global_load_lds(
        (const __attribute__((address_space(1))) u32*)gmem,
        (__attribute__((address_space(3))) u32*)lds, 16, 0, 0);
}

// raw barrier (NO vmcnt drain) + compiler memory fences so plain-C++ ds_reads
// cannot be hoisted/sunk across it at IR level.
#define BAR() do { asm volatile("" ::: "memory"); \
                   __builtin_amdgcn_s_barrier();  \
                   asm volatile("" ::: "memory"); } while (0)
#define VMCNT(N) asm volatile("s_waitcnt vmcnt(" #N ")" ::: "memory")

// ---------------------------------------------------------------------------
// x (f32) -> bf16, 8 elems/thread/iter
// ---------------------------------------------------------------------------
__global__ void cvt_x_kernel(const float* __restrict__ in,
                             bf16_t* __restrict__ out, int n8) {
    int stride = gridDim.x * blockDim.x;
    for (int i = blockIdx.x * blockDim.x + threadIdx.x; i < n8; i += stride) {
        const float4* p = (const float4*)in + 2 * (size_t)i;
        float4 a = p[0], b = p[1];
        bf16x8 o;
        o[0] = (__bf16)a.x; o[1] = (__bf16)a.y; o[2] = (__bf16)a.z; o[3] = (__bf16)a.w;
        o[4] = (__bf16)b.x; o[5] = (__bf16)b.y; o[6] = (__bf16)b.z; o[7] = (__bf16)b.w;
        *(bf16x8*)(out + 8 * (size_t)i) = o;
    }
}

// ---------------------------------------------------------------------------
// w (f32) * per-128x128-block scale -> bf16 (scale folded into weight)
// ---------------------------------------------------------------------------
__global__ void cvt_w_kernel(const float* __restrict__ w,
                             const float* __restrict__ wsc,
                             bf16_t* __restrict__ out, int n8, int K, int KB) {
    int stride = gridDim.x * blockDim.x;
    for (int i = blockIdx.x * blockDim.x + threadIdx.x; i < n8; i += stride) {
        int e = i * 8;
        int row = e / K;
        int col = e - row * K;
        float s = wsc[(row >> 7) * KB + (col >> 7)];
        const float4* p = (const float4*)w + 2 * (size_t)i;
        float4 a = p[0], b = p[1];
        bf16x8 o;
        o[0] = (__bf16)(a.x * s); o[1] = (__bf16)(a.y * s);
        o[2] = (__bf16)(a.z * s); o[3] = (__bf16)(a.w * s);
        o[4] = (__bf16)(b.x * s); o[5] = (__bf16)(b.y * s);
        o[6] = (__bf16)(b.z * s); o[7] = (__bf16)(b.w * s);
        *(bf16x8*)(out + 8 * (size_t)i) = o;
    }
}

// ===========================================================================
// 256x256x64 8-phase GEMM (m201 template, plain HIP):
//   8 waves (2M x 4N), per-wave 128x64 output = acc[8][4] f32x4.
//   LDS 128 KiB: buf{0,1} x (A[256][64] | B[256][64]) bf16, st_16x32 swizzle
//   (byte ^= ((byte>>9)&1)<<5  ==  col-byte ^= 32 iff row&4), applied on the
//   pre-swizzled GLOBAL source (stage) and on the ds_read address (read).
//   Phases per K-tile kt (cur=kt&1):
//     ph0: rd A[m0..3]x2ks + B[n0..1]x2ks | stage A0(kt+1)->buf[cur^1] | MFMA m0-3 x n0-1
//     ph1: rd B[n2..3]                    | stage A1(kt+1)             | MFMA m0-3 x n2-3
//     ph2: rd A[m4..7]                    | stage B0(kt+2)->buf[cur]   | MFMA m4-7 x n2-3
//     ph3: (reuse regs)                   | stage B1(kt+2)             | MFMA m4-7 x n0-1
//          vmcnt(4)  (kt+1's A/B fully landed; only B(kt+2) in flight)  barrier
//   Region-death proof: buf[cur] B dead after ph1 (staged ph2/3);
//   buf[cur^1] A dead since (kt-1).ph2 (staged ph0/1). Tail stages clamped
//   to nt-1 (redundant loads into never-again-read regions) so the vmcnt
//   count invariant is branch-free.
// ===========================================================================
__global__ __launch_bounds__(512, 2) void gemm256_8ph(
    const bf16_t* __restrict__ A,   // [M,K] bf16
    const bf16_t* __restrict__ B,   // [N,K] bf16 (scale-folded weight)
    const float* __restrict__ bias, // [N]
    float* __restrict__ C,          // [M,N] f32
    int M, int N, int K, int tiles_n) {
    __shared__ __attribute__((aligned(16))) char smem[131072];

    const int tid = threadIdx.x;
    const int lane = tid & 63;
    const int wv = tid >> 6;
    const int wr = wv >> 2;          // 0..1
    const int wc = wv & 3;           // 0..3
    const int la = lane & 15;
    const int hi = lane >> 4;

    // bijective XCD swizzle (grid % 8 == 0 on this shape)
    const int nwg = gridDim.x;
    int wg = blockIdx.x;
    if ((nwg & 7) == 0) wg = (wg & 7) * (nwg >> 3) + (wg >> 3);
    const int tm = wg / tiles_n, tn = wg % tiles_n;

    const long arow = (long)tm * 256;
    const long bcol = (long)tn * 256;

    // staging source (pre-swizzled): dest row = h*128 + l*64 + (tid>>3),
    // dest col-byte = (tid&7)*16; swizzle flips bit5 iff row&4 <=> tid&32.
    const int srow = tid >> 3;
    const int scolb = ((tid & 7) * 16) ^ ((tid & 32) ? 32 : 0);
    const size_t rstep = (size_t)K * 2;
    const char* pa = (const char*)A + (size_t)(arow + srow) * rstep + scolb;
    const char* pb = (const char*)B + (size_t)(bcol + srow) * rstep + scolb;
    char* const lb = (char*)smem;
    const int ldst = tid * 16;

    // ds_read lane offsets, swizzle flips byte-bit5 iff row&4 (= lane&4)
    const int swz = (lane & 4) << 3;
    const int aoff = (((wr * 128 + la) * 128) + hi * 16) ^ swz;
    const int boff = (((wc * 64 + la) * 128) + hi * 16) ^ swz;

#define STAGE_A(BUF, H, KT) do { \
        const char* _s = pa + (size_t)(KT) * 128 + (size_t)(H) * 128 * rstep; \
        char* _d = lb + (BUF) * 65536 + (H) * 16384 + ldst; \
        async_copy16(_d, _s); \
        async_copy16(_d + 8192, _s + 64 * rstep); \
    } while (0)
#define STAGE_B(BUF, H, KT) do { \
        const char* _s = pb + (size_t)(KT) * 128 + (size_t)(H) * 128 * rstep; \
        char* _d = lb + (BUF) * 65536 + 32768 + (H) * 16384 + ldst; \
        async_copy16(_d, _s); \
        async_copy16(_d + 8192, _s + 64 * rstep); \
    } while (0)
#define RD_A(BUF, MM, KS) (*(const bf16x8*)(lb + (BUF) * 65536 + (aoff + (MM) * 2048 + (KS) * 64)))
#define RD_B(BUF, NN, KS) (*(const bf16x8*)(lb + (BUF) * 65536 + 32768 + (boff + (NN) * 2048 + (KS) * 64)))

    f32x4 acc[8][4];
#pragma unroll
    for (int m = 0; m < 8; ++m)
#pragma unroll
        for (int n = 0; n < 4; ++n) {
            f32x4 z = {0.f, 0.f, 0.f, 0.f};
            acc[m][n] = z;
        }
    bf16x8 a[4][2], b0[2][2], b1[2][2];

    const int nt = K >> 6;           // K-tiles (>= 2, even: K % 128 == 0)

    // prologue: K-tile 0 fully + B halves of K-tile 1 (steady-state invariant)
    STAGE_A(0, 0, 0); STAGE_A(0, 1, 0);
    STAGE_B(0, 0, 0); STAGE_B(0, 1, 0);
    STAGE_B(1, 0, 1); STAGE_B(1, 1, 1);
    VMCNT(4);
    BAR();

    for (int kt = 0; kt < nt; kt += 2) {
#define KTILE(CUR, KTV) do { \
        const int _ktA = ((KTV) + 1 < nt) ? (KTV) + 1 : nt - 1; \
        const int _ktB = ((KTV) + 2 < nt) ? (KTV) + 2 : nt - 1; \
        /* -------- phase 0 -------- */ \
        _Pragma("unroll") for (int m = 0; m < 4; ++m) { a[m][0] = RD_A(CUR, m, 0); a[m][1] = RD_A(CUR, m, 1); } \
        _Pragma("unroll") for (int n = 0; n < 2; ++n) { b0[n][0] = RD_B(CUR, n, 0); b0[n][1] = RD_B(CUR, n, 1); } \
        STAGE_A((CUR) ^ 1, 0, _ktA); \
        BAR(); \
        __builtin_amdgcn_s_setprio(1); \
        _Pragma("unroll") for (int ks = 0; ks < 2; ++ks) \
            _Pragma("unroll") for (int m = 0; m < 4; ++m) \
                _Pragma("unroll") for (int n = 0; n < 2; ++n) \
                    acc[m][n] = __builtin_amdgcn_mfma_f32_16x16x32_bf16(a[m][ks], b0[n][ks], acc[m][n], 0, 0, 0); \
        __builtin_amdgcn_s_setprio(0); \
        BAR(); \
        /* -------- phase 1 -------- */ \
        _Pragma("unroll") for (int n = 0; n < 2; ++n) { b1[n][0] = RD_B(CUR, 2 + n, 0); b1[n][1] = RD_B(CUR, 2 + n, 1); } \
        STAGE_A((CUR) ^ 1, 1, _ktA); \
        BAR(); \
        __builtin_amdgcn_s_setprio(1); \
        _Pragma("unroll") for (int ks = 0; ks < 2; ++ks) \
            _Pragma("unroll") for (int m = 0; m < 4; ++m) \
                _Pragma("unroll") for (int n = 0; n < 2; ++n) \
                    acc[m][2 + n] = __builtin_amdgcn_mfma_f32_16x16x32_bf16(a[m][ks], b1[n][ks], acc[m][2 + n], 0, 0, 0); \
        __builtin_amdgcn_s_setprio(0); \
        BAR(); \
        /* -------- phase 2 -------- */ \
        _Pragma("unroll") for (int m = 0; m < 4; ++m) { a[m][0] = RD_A(CUR, 4 + m, 0); a[m][1] = RD_A(CUR, 4 + m, 1); } \
        STAGE_B(CUR, 0, _ktB); \
        BAR(); \
        __builtin_amdgcn_s_setprio(1); \
        _Pragma("unroll") for (int ks = 0; ks < 2; ++ks) \
            _Pragma("unroll") for (int m = 0; m < 4; ++m) \
                _Pragma("unroll") for (int n = 0; n < 2; ++n) \
                    acc[4 + m][2 + n] = __builtin_amdgcn_mfma_f32_16x16x32_bf16(a[m][ks], b1[n][ks], acc[4 + m][2 + n], 0, 0, 0); \
        __builtin_amdgcn_s_setprio(0); \
        BAR(); \
        /* -------- phase 3 -------- */ \
        STAGE_B(CUR, 1, _ktB); \
        BAR(); \
        __builtin_amdgcn_s_setprio(1); \
        _Pragma("unroll") for (int ks = 0; ks < 2; ++ks) \
            _Pragma("unroll") for (int m = 0; m < 4; ++m) \
                _Pragma("unroll") for (int n = 0; n < 2; ++n) \
                    acc[4 + m][n] = __builtin_amdgcn_mfma_f32_16x16x32_bf16(a[m][ks], b0[n][ks], acc[4 + m][n], 0, 0, 0); \
        __builtin_amdgcn_s_setprio(0); \
        VMCNT(4); \
        BAR(); \
    } while (0)
        KTILE(0, kt);
        KTILE(1, kt + 1);
#undef KTILE
    }

    // epilogue: D col = lane&15, row = 4*(lane>>4) + reg  [m89-verified]
    const float* bp = bias + bcol + wc * 64 + la;
    const float bv0 = bp[0], bv1 = bp[16], bv2 = bp[32], bv3 = bp[48];
    float* cbase = C + (arow + wr * 128 + hi * 4) * (long)N + bcol + wc * 64 + la;
#pragma unroll
    for (int m = 0; m < 8; ++m)
#pragma unroll
        for (int r = 0; r < 4; ++r) {
            float* cp = cbase + (size_t)(m * 16 + r) * N;
            cp[0]  = acc[m][0][r] + bv0;
            cp[16] = acc[m][1][r] + bv1;
            cp[32] = acc[m][2][r] + bv2;
            cp[48] = acc[m][3][r] + bv3;
        }
#undef STAGE_A
#undef STAGE_B
#undef RD_A
#undef RD_B
}

// ---------------------------------------------------------------------------
// m97-structure 128x128 GEMM — fallback for 128-divisible (not 256) shapes
// ---------------------------------------------------------------------------
__global__ __launch_bounds__(256) void gemm_bt_bias(
    const bf16_t* __restrict__ A, const bf16_t* __restrict__ B,
    const float* __restrict__ bias, float* __restrict__ C,
    int M, int N, int K) {
    __shared__ bf16_t As[128 * 32];
    __shared__ bf16_t Bs[128 * 32];
    const int t = threadIdx.x;
    const int lane = t & 63;
    const int wave = t >> 6;
    const int wr = wave >> 1, wc = wave & 1;
    const long arow = (long)blockIdx.y * 128;
    const long bcol = (long)blockIdx.x * 128;
    const int r0 = t >> 2, c0 = (t & 3) * 8;
    const bf16_t* Ag = A + (arow + r0) * K + c0;
    const bf16_t* Bg = B + (bcol + r0) * K + c0;
    bf16_t* Al = As + t * 8;
    bf16_t* Bl = Bs + t * 8;
    const size_t gstep = (size_t)64 * K;
    f32x4 acc[4][4];
#pragma unroll
    for (int m = 0; m < 4; ++m)
#pragma unroll
        for (int n = 0; n < 4; ++n) { f32x4 z = {0.f,0.f,0.f,0.f}; acc[m][n] = z; }
    const int la = lane & 15, kg = (lane >> 4) * 8;
    for (int k0 = 0; k0 < K; k0 += 32) {
        async_copy16(Al, Ag + k0);        async_copy16(Al + 2048, Ag + k0 + gstep);
        async_copy16(Bl, Bg + k0);        async_copy16(Bl + 2048, Bg + k0 + gstep);
        __syncthreads();
        bf16x8 af[4], bfv[4];
#pragma unroll
        for (int m = 0; m < 4; ++m) af[m]  = *(const bf16x8*)(As + (wr*64 + m*16 + la)*32 + kg);
#pragma unroll
        for (int n = 0; n < 4; ++n) bfv[n] = *(const bf16x8*)(Bs + (wc*64 + n*16 + la)*32 + kg);
#pragma unroll
        for (int m = 0; m < 4; ++m)
#pragma unroll
            for (int n = 0; n < 4; ++n)
                acc[m][n] = __builtin_amdgcn_mfma_f32_16x16x32_bf16(af[m], bfv[n], acc[m][n], 0,0,0);
        __syncthreads();
    }
    const int lg = lane >> 4;
#pragma unroll
    for (int n = 0; n < 4; ++n) {
        const long col = bcol + wc * 64 + n * 16 + la;
        const float bv = bias[col];
#pragma unroll
        for (int m = 0; m < 4; ++m) {
            const long row = arow + wr * 64 + m * 16 + lg * 4;
            float* cp = C + row * (long)N + col;
#pragma unroll
            for (int r = 0; r < 4; ++r) cp[(size_t)r * N] = acc[m][n][r] + bv;
        }
    }
}

// ---------------------------------------------------------------------------
// fully-general fallback
// ---------------------------------------------------------------------------
__global__ void naive_kernel(const float* __restrict__ x, const float* __restrict__ w,
                             const float* __restrict__ wsc, const float* __restrict__ bias,
                             float* __restrict__ out, int T, int N, int K, int KB) {
    long i = (long)blockIdx.x * blockDim.x + threadIdx.x;
    if (i >= (long)T * N) return;
    int tt = (int)(i / N), n = (int)(i % N);
    float accum = 0.f;
    for (int kb = 0; kb < KB; ++kb) {
        float s = wsc[(n >> 7) * KB + kb];
        float p = 0.f;
        const float* xp = x + (long)tt * K + kb * 128;
        const float* wp = w + (long)n * K + kb * 128;
        for (int k = 0; k < 128; ++k) p += xp[k] * wp[k];
        accum += p * s;
    }
    out[i] = accum + bias[n];
}

extern "C" void kernel_launch(void* const* d_in, const int* in_sizes, int n_in,
                              void* d_out, int out_size, void* d_ws, size_t ws_size,
                              hipStream_t stream) {
    const float* x    = (const float*)d_in[0];
    const float* wq   = (const float*)d_in[1];
    const float* wsc  = (const float*)d_in[2];
    const float* bias = (const float*)d_in[3];
    float* out = (float*)d_out;

    const int N = in_sizes[3];
    const int K = in_sizes[1] / N;
    const int T = in_sizes[0] / K;
    const int KB = K / 128;

    const size_t need = ((size_t)T * K + (size_t)N * K) * sizeof(bf16_t);
    const bool t256 = (T % 256 == 0) && (N % 256 == 0) && (K % 128 == 0) && (K >= 128);
    const bool t128 = (T % 128 == 0) && (N % 128 == 0) && (K % 32 == 0) && (K % 128 == 0);

    if (ws_size < need || (!t256 && !t128)) {
        long total = (long)T * N;
        naive_kernel<<<(int)((total + 255) / 256), 256, 0, stream>>>(
            x, wq, wsc, bias, out, T, N, K, KB);
        return;
    }

    bf16_t* xb = (bf16_t*)d_ws;
    bf16_t* wb = xb + (size_t)T * K;

    cvt_x_kernel<<<2048, 256, 0, stream>>>(x, xb, T * (K / 8));
    cvt_w_kernel<<<2048, 256, 0, stream>>>(wq, wsc, wb, N * (K / 8), K, KB);

    if (t256) {
        const int tiles_n = N / 256;
        const int nwg = (T / 256) * tiles_n;
        gemm256_8ph<<<nwg, 512, 0, stream>>>(xb, wb, bias, out, T, N, K, tiles_n);
    } else {
        dim3 grid(N / 128, T / 128);
        gemm_bt_bias<<<grid, 256, 0, stream>>>(xb, wb, bias, out, T, N, K);
    }
}

// Round 4
// 463.223 us; speedup vs baseline: 1.4619x; 1.0742x over previous
//
#include <hip/hip_runtime.h>
#include <hip/hip_bf16.h>
#include <stdint.h>

typedef __bf16 bf16_t;
typedef __bf16 bf16x8 __attribute__((ext_vector_type(8)));
typedef float f32x4 __attribute__((ext_vector_type(4)));
typedef unsigned int u32;

// ---------------------------------------------------------------------------
// async global->LDS, 16B per lane. HW dest = wave-uniform base + lane*16;
// we pass per-lane ptr linear in tid so lane stride is exactly 16B.
// Global SOURCE is per-lane -> swizzled LDS content via pre-swizzled source.
// ---------------------------------------------------------------------------
__device__ __forceinline__ void async_copy16(void* lds, const void* gmem) {
    __builtin_amdgcn_global_load_lds(
        (const __attribute__((address_space(1))) u32*)gmem,
        (__attribute__((address_space(3))) u32*)lds, 16, 0, 0);
}

// raw barrier (NO vmcnt drain) + compiler memory fences
#define BAR() do { asm volatile("" ::: "memory"); \
                   __builtin_amdgcn_s_barrier();  \
                   asm volatile("" ::: "memory"); } while (0)
#define VMCNT(N) asm volatile("s_waitcnt vmcnt(" #N ")" ::: "memory")

// ---------------------------------------------------------------------------
// fused conversion: x (f32->bf16) and w (f32 * blockscale -> bf16), one launch
// nontemporal f32 loads (inputs never re-read; keep L3 for the bf16 ws)
// ---------------------------------------------------------------------------
__global__ void cvt_fused(const float* __restrict__ x,
                          const float* __restrict__ w,
                          const float* __restrict__ wsc,
                          bf16_t* __restrict__ xb, bf16_t* __restrict__ wb,
                          int nx8, int nw8, int K, int KB) {
    int stride = gridDim.x * blockDim.x;
    int ntot = nx8 + nw8;
    for (int i = blockIdx.x * blockDim.x + threadIdx.x; i < ntot; i += stride) {
        if (i < nx8) {
            const f32x4* p = (const f32x4*)x + 2 * (size_t)i;
            f32x4 a = __builtin_nontemporal_load(p);
            f32x4 b = __builtin_nontemporal_load(p + 1);
            bf16x8 o;
            o[0] = (__bf16)a[0]; o[1] = (__bf16)a[1]; o[2] = (__bf16)a[2]; o[3] = (__bf16)a[3];
            o[4] = (__bf16)b[0]; o[5] = (__bf16)b[1]; o[6] = (__bf16)b[2]; o[7] = (__bf16)b[3];
            *(bf16x8*)(xb + 8 * (size_t)i) = o;
        } else {
            int j = i - nx8;
            int e = j * 8;
            int row = e / K;
            int col = e - row * K;
            float s = wsc[(row >> 7) * KB + (col >> 7)];
            const f32x4* p = (const f32x4*)w + 2 * (size_t)j;
            f32x4 a = __builtin_nontemporal_load(p);
            f32x4 b = __builtin_nontemporal_load(p + 1);
            bf16x8 o;
            o[0] = (__bf16)(a[0] * s); o[1] = (__bf16)(a[1] * s);
            o[2] = (__bf16)(a[2] * s); o[3] = (__bf16)(a[3] * s);
            o[4] = (__bf16)(b[0] * s); o[5] = (__bf16)(b[1] * s);
            o[6] = (__bf16)(b[2] * s); o[7] = (__bf16)(b[3] * s);
            *(bf16x8*)(wb + 8 * (size_t)j) = o;
        }
    }
}

// ===========================================================================
// 256x256x64 8-phase GEMM (m201 template):
//   8 waves (2M x 4N), per-wave 128x64 output = acc[8][4] f32x4.
//   LDS 128 KiB: buf{0,1} x (A[256][64] | B[256][64]) bf16.
//   Swizzle (G4 form for 128B rows + b128 reads): byte ^= (row&7)<<4,
//   applied on the pre-swizzled GLOBAL source (stage) and on the ds_read
//   column-byte (cb0/cb1 precomputed per K-slot so no carry past bit 6).
//   Phases per K-tile kt (cur=kt&1):
//     ph0: rd A[m0..3] + B[n0..1] | stage A0(kt+1)->buf[cur^1] | MFMA m0-3 x n0-1
//     ph1: rd B[n2..3]            | stage A1(kt+1)             | MFMA m0-3 x n2-3
//     ph2: rd A[m4..7]            | stage B0(kt+2)->buf[cur]   | MFMA m4-7 x n2-3
//     ph3: (reuse regs)           | stage B1(kt+2)             | MFMA m4-7 x n0-1
//          vmcnt(4) (kt+1 landed; only B(kt+2) in flight), barrier
// ===========================================================================
__global__ __launch_bounds__(512, 2) void gemm256_8ph(
    const bf16_t* __restrict__ A,   // [M,K] bf16
    const bf16_t* __restrict__ B,   // [N,K] bf16 (scale-folded weight)
    const float* __restrict__ bias, // [N]
    float* __restrict__ C,          // [M,N] f32
    int M, int N, int K, int tiles_n) {
    __shared__ __attribute__((aligned(16))) char smem[131072];

    const int tid = threadIdx.x;
    const int lane = tid & 63;
    const int wv = tid >> 6;
    const int wr = wv >> 2;          // 0..1
    const int wc = wv & 3;           // 0..3
    const int la = lane & 15;
    const int hi = lane >> 4;

    // bijective XCD swizzle (grid % 8 == 0 on this shape)
    const int nwg = gridDim.x;
    int wg = blockIdx.x;
    if ((nwg & 7) == 0) wg = (wg & 7) * (nwg >> 3) + (wg >> 3);
    const int tm = wg / tiles_n, tn = wg % tiles_n;

    const long arow = (long)tm * 256;
    const long bcol = (long)tn * 256;

    // staging source (pre-swizzled): dest row = tid>>3 (+64/+128 multiples),
    // dest col-byte = (tid&7)*16; swizzle XORs (row&7)<<4 into col-byte.
    const int srow = tid >> 3;
    const int scolb = ((tid & 7) * 16) ^ (((tid >> 3) & 7) << 4);
    const size_t rstep = (size_t)K * 2;
    const char* pa = (const char*)A + (size_t)(arow + srow) * rstep + scolb;
    const char* pb = (const char*)B + (size_t)(bcol + srow) * rstep + scolb;
    char* const lb = (char*)smem;
    const int ldst = tid * 16;

    // ds_read: row&7 == la&7 for all A and B fragment rows; column-byte for
    // K-slot ks is (hi*16 + ks*64) ^ ((la&7)<<4). Precompute both slots.
    const int swz = (la & 7) << 4;
    const int cb0 = (hi * 16) ^ swz;     // ks=0
    const int cb1 = cb0 ^ 64;            // ks=1 (bit6 of hi*16 is 0)
    const int arowoff = (wr * 128 + la) * 128;
    const int browoff = 32768 + (wc * 64 + la) * 128;

#define STAGE_A(BUF, H, KT) do { \
        const char* _s = pa + (size_t)(KT) * 128 + (size_t)(H) * 128 * rstep; \
        char* _d = lb + (BUF) * 65536 + (H) * 16384 + ldst; \
        async_copy16(_d, _s); \
        async_copy16(_d + 8192, _s + 64 * rstep); \
    } while (0)
#define STAGE_B(BUF, H, KT) do { \
        const char* _s = pb + (size_t)(KT) * 128 + (size_t)(H) * 128 * rstep; \
        char* _d = lb + (BUF) * 65536 + 32768 + (H) * 16384 + ldst; \
        async_copy16(_d, _s); \
        async_copy16(_d + 8192, _s + 64 * rstep); \
    } while (0)
#define RD_A(BUF, MM, CB) (*(const bf16x8*)(lb + (BUF) * 65536 + arowoff + (MM) * 2048 + (CB)))
#define RD_B(BUF, NN, CB) (*(const bf16x8*)(lb + (BUF) * 65536 + browoff + (NN) * 2048 + (CB)))

    f32x4 acc[8][4];
#pragma unroll
    for (int m = 0; m < 8; ++m)
#pragma unroll
        for (int n = 0; n < 4; ++n) {
            f32x4 z = {0.f, 0.f, 0.f, 0.f};
            acc[m][n] = z;
        }
    bf16x8 a[4][2], b0[2][2], b1[2][2];

    const int nt = K >> 6;           // K-tiles (>= 2, even: K % 128 == 0)

    // prologue: K-tile 0 fully + B halves of K-tile 1 (steady-state invariant)
    STAGE_A(0, 0, 0); STAGE_A(0, 1, 0);
    STAGE_B(0, 0, 0); STAGE_B(0, 1, 0);
    STAGE_B(1, 0, 1); STAGE_B(1, 1, 1);
    VMCNT(4);
    BAR();

    for (int kt = 0; kt < nt; kt += 2) {
#define KTILE(CUR, KTV) do { \
        const int _ktA = ((KTV) + 1 < nt) ? (KTV) + 1 : nt - 1; \
        const int _ktB = ((KTV) + 2 < nt) ? (KTV) + 2 : nt - 1; \
        /* -------- phase 0 -------- */ \
        _Pragma("unroll") for (int m = 0; m < 4; ++m) { a[m][0] = RD_A(CUR, m, cb0); a[m][1] = RD_A(CUR, m, cb1); } \
        _Pragma("unroll") for (int n = 0; n < 2; ++n) { b0[n][0] = RD_B(CUR, n, cb0); b0[n][1] = RD_B(CUR, n, cb1); } \
        STAGE_A((CUR) ^ 1, 0, _ktA); \
        BAR(); \
        __builtin_amdgcn_s_setprio(1); \
        _Pragma("unroll") for (int ks = 0; ks < 2; ++ks) \
            _Pragma("unroll") for (int m = 0; m < 4; ++m) \
                _Pragma("unroll") for (int n = 0; n < 2; ++n) \
                    acc[m][n] = __builtin_amdgcn_mfma_f32_16x16x32_bf16(a[m][ks], b0[n][ks], acc[m][n], 0, 0, 0); \
        __builtin_amdgcn_s_setprio(0); \
        BAR(); \
        /* -------- phase 1 -------- */ \
        _Pragma("unroll") for (int n = 0; n < 2; ++n) { b1[n][0] = RD_B(CUR, 2 + n, cb0); b1[n][1] = RD_B(CUR, 2 + n, cb1); } \
        STAGE_A((CUR) ^ 1, 1, _ktA); \
        BAR(); \
        __builtin_amdgcn_s_setprio(1); \
        _Pragma("unroll") for (int ks = 0; ks < 2; ++ks) \
            _Pragma("unroll") for (int m = 0; m < 4; ++m) \
                _Pragma("unroll") for (int n = 0; n < 2; ++n) \
                    acc[m][2 + n] = __builtin_amdgcn_mfma_f32_16x16x32_bf16(a[m][ks], b1[n][ks], acc[m][2 + n], 0, 0, 0); \
        __builtin_amdgcn_s_setprio(0); \
        BAR(); \
        /* -------- phase 2 -------- */ \
        _Pragma("unroll") for (int m = 0; m < 4; ++m) { a[m][0] = RD_A(CUR, 4 + m, cb0); a[m][1] = RD_A(CUR, 4 + m, cb1); } \
        STAGE_B(CUR, 0, _ktB); \
        BAR(); \
        __builtin_amdgcn_s_setprio(1); \
        _Pragma("unroll") for (int ks = 0; ks < 2; ++ks) \
            _Pragma("unroll") for (int m = 0; m < 4; ++m) \
                _Pragma("unroll") for (int n = 0; n < 2; ++n) \
                    acc[4 + m][2 + n] = __builtin_amdgcn_mfma_f32_16x16x32_bf16(a[m][ks], b1[n][ks], acc[4 + m][2 + n], 0, 0, 0); \
        __builtin_amdgcn_s_setprio(0); \
        BAR(); \
        /* -------- phase 3 -------- */ \
        STAGE_B(CUR, 1, _ktB); \
        BAR(); \
        __builtin_amdgcn_s_setprio(1); \
        _Pragma("unroll") for (int ks = 0; ks < 2; ++ks) \
            _Pragma("unroll") for (int m = 0; m < 4; ++m) \
                _Pragma("unroll") for (int n = 0; n < 2; ++n) \
                    acc[4 + m][n] = __builtin_amdgcn_mfma_f32_16x16x32_bf16(a[m][ks], b0[n][ks], acc[4 + m][n], 0, 0, 0); \
        __builtin_amdgcn_s_setprio(0); \
        VMCNT(4); \
        BAR(); \
    } while (0)
        KTILE(0, kt);
        KTILE(1, kt + 1);
#undef KTILE
    }

    // epilogue: D col = lane&15, row = 4*(lane>>4) + reg  [m89-verified]
    const float* bp = bias + bcol + wc * 64 + la;
    const float bv0 = bp[0], bv1 = bp[16], bv2 = bp[32], bv3 = bp[48];
    float* cbase = C + (arow + wr * 128 + hi * 4) * (long)N + bcol + wc * 64 + la;
#pragma unroll
    for (int m = 0; m < 8; ++m)
#pragma unroll
        for (int r = 0; r < 4; ++r) {
            float* cp = cbase + (size_t)(m * 16 + r) * N;
            cp[0]  = acc[m][0][r] + bv0;
            cp[16] = acc[m][1][r] + bv1;
            cp[32] = acc[m][2][r] + bv2;
            cp[48] = acc[m][3][r] + bv3;
        }
#undef STAGE_A
#undef STAGE_B
#undef RD_A
#undef RD_B
}

// ---------------------------------------------------------------------------
// m97-structure 128x128 GEMM — fallback for 128-divisible (not 256) shapes
// ---------------------------------------------------------------------------
__global__ __launch_bounds__(256) void gemm_bt_bias(
    const bf16_t* __restrict__ A, const bf16_t* __restrict__ B,
    const float* __restrict__ bias, float* __restrict__ C,
    int M, int N, int K) {
    __shared__ bf16_t As[128 * 32];
    __shared__ bf16_t Bs[128 * 32];
    const int t = threadIdx.x;
    const int lane = t & 63;
    const int wave = t >> 6;
    const int wr = wave >> 1, wc = wave & 1;
    const long arow = (long)blockIdx.y * 128;
    const long bcol = (long)blockIdx.x * 128;
    const int r0 = t >> 2, c0 = (t & 3) * 8;
    const bf16_t* Ag = A + (arow + r0) * K + c0;
    const bf16_t* Bg = B + (bcol + r0) * K + c0;
    bf16_t* Al = As + t * 8;
    bf16_t* Bl = Bs + t * 8;
    const size_t gstep = (size_t)64 * K;
    f32x4 acc[4][4];
#pragma unroll
    for (int m = 0; m < 4; ++m)
#pragma unroll
        for (int n = 0; n < 4; ++n) { f32x4 z = {0.f,0.f,0.f,0.f}; acc[m][n] = z; }
    const int la = lane & 15, kg = (lane >> 4) * 8;
    for (int k0 = 0; k0 < K; k0 += 32) {
        async_copy16(Al, Ag + k0);        async_copy16(Al + 2048, Ag + k0 + gstep);
        async_copy16(Bl, Bg + k0);        async_copy16(Bl + 2048, Bg + k0 + gstep);
        __syncthreads();
        bf16x8 af[4], bfv[4];
#pragma unroll
        for (int m = 0; m < 4; ++m) af[m]  = *(const bf16x8*)(As + (wr*64 + m*16 + la)*32 + kg);
#pragma unroll
        for (int n = 0; n < 4; ++n) bfv[n] = *(const bf16x8*)(Bs + (wc*64 + n*16 + la)*32 + kg);
#pragma unroll
        for (int m = 0; m < 4; ++m)
#pragma unroll
            for (int n = 0; n < 4; ++n)
                acc[m][n] = __builtin_amdgcn_mfma_f32_16x16x32_bf16(af[m], bfv[n], acc[m][n], 0,0,0);
        __syncthreads();
    }
    const int lg = lane >> 4;
#pragma unroll
    for (int n = 0; n < 4; ++n) {
        const long col = bcol + wc * 64 + n * 16 + la;
        const float bv = bias[col];
#pragma unroll
        for (int m = 0; m < 4; ++m) {
            const long row = arow + wr * 64 + m * 16 + lg * 4;
            float* cp = C + row * (long)N + col;
#pragma unroll
            for (int r = 0; r < 4; ++r) cp[(size_t)r * N] = acc[m][n][r] + bv;
        }
    }
}

// ---------------------------------------------------------------------------
// fully-general fallback
// ---------------------------------------------------------------------------
__global__ void naive_kernel(const float* __restrict__ x, const float* __restrict__ w,
                             const float* __restrict__ wsc, const float* __restrict__ bias,
                             float* __restrict__ out, int T, int N, int K, int KB) {
    long i = (long)blockIdx.x * blockDim.x + threadIdx.x;
    if (i >= (long)T * N) return;
    int tt = (int)(i / N), n = (int)(i % N);
    float accum = 0.f;
    for (int kb = 0; kb < KB; ++kb) {
        float s = wsc[(n >> 7) * KB + kb];
        float p = 0.f;
        const float* xp = x + (long)tt * K + kb * 128;
        const float* wp = w + (long)n * K + kb * 128;
        for (int k = 0; k < 128; ++k) p += xp[k] * wp[k];
        accum += p * s;
    }
    out[i] = accum + bias[n];
}

extern "C" void kernel_launch(void* const* d_in, const int* in_sizes, int n_in,
                              void* d_out, int out_size, void* d_ws, size_t ws_size,
                              hipStream_t stream) {
    const float* x    = (const float*)d_in[0];
    const float* wq   = (const float*)d_in[1];
    const float* wsc  = (const float*)d_in[2];
    const float* bias = (const float*)d_in[3];
    float* out = (float*)d_out;

    const int N = in_sizes[3];
    const int K = in_sizes[1] / N;
    const int T = in_sizes[0] / K;
    const int KB = K / 128;

    const size_t need = ((size_t)T * K + (size_t)N * K) * sizeof(bf16_t);
    const bool t256 = (T % 256 == 0) && (N % 256 == 0) && (K % 128 == 0) && (K >= 128);
    const bool t128 = (T % 128 == 0) && (N % 128 == 0) && (K % 32 == 0) && (K % 128 == 0);

    if (ws_size < need || (!t256 && !t128)) {
        long total = (long)T * N;
        naive_kernel<<<(int)((total + 255) / 256), 256, 0, stream>>>(
            x, wq, wsc, bias, out, T, N, K, KB);
        return;
    }

    bf16_t* xb = (bf16_t*)d_ws;
    bf16_t* wb = xb + (size_t)T * K;

    cvt_fused<<<2048, 256, 0, stream>>>(x, wq, wsc, xb, wb,
                                        T * (K / 8), N * (K / 8), K, KB);

    if (t256) {
        const int tiles_n = N / 256;
        const int nwg = (T / 256) * tiles_n;
        gemm256_8ph<<<nwg, 512, 0, stream>>>(xb, wb, bias, out, T, N, K, tiles_n);
    } else {
        dim3 grid(N / 128, T / 128);
        gemm_bt_bias<<<grid, 256, 0, stream>>>(xb, wb, bias, out, T, N, K);
    }
}